// Round 6
// baseline (407.792 us; speedup 1.0000x reference)
//
#include <hip/hip_runtime.h>
#include <math.h>

#define NUM_CLASSES 10
#define GRID_H 80
#define GRID_W 80
#define NCELLS (GRID_H * GRID_W)
#define NBOX 64
#define SEG (1024 * 1024)   // Hs*Ws per (batch[,channel])
#define XBLK 64
#define TPB 256
#define ITERS 8             // 64 blk * 256 thr * 8 elem * 8 iter == SEG
#define CHUNK_F4 32768      // per-iter stride in float4 units: 64*256*8/4

// ws layout (doubles):
//  0..7    obj_sum[b]
//  8..15   box_sum[b]
// 16..23   cls_sum[b]
// 24..31   npos[b]
// 32..39   da_sum[b]
// 40..47   da_cnt[b]
// 48..71   rm_focal[b*3+c]
// 72..95   rm_inter[ch]
// 96..119  rm_probsum[ch]
// 120..143 rm_rtsum[ch]
// 144..167 rm_cnt[ch]
#define WS_DOUBLES 168

__device__ __forceinline__ void reduce_atomic(double v, double* gdst, double* smem) {
    #pragma unroll
    for (int off = 32; off > 0; off >>= 1) v += __shfl_down(v, off, 64);
    int lane = threadIdx.x & 63, wid = threadIdx.x >> 6;
    __syncthreads();               // protect smem reuse across successive calls
    if (lane == 0) smem[wid] = v;
    __syncthreads();
    if (threadIdx.x == 0) {
        double s = 0.0;
        int nw = blockDim.x >> 6;
        for (int i = 0; i < nw; i++) s += smem[i];
        atomicAdd(gdst, s);
    }
}

// one element of rm/da math; t in {0,1}; is_rm selects focal weighting
__device__ __forceinline__ void elem_one(float x, int m, bool is_rm,
        float& lsum, float& inter, float& ps, float& ts, float& cnt) {
    const float vf = (m != 255) ? 1.0f : 0.0f;
    const float t  = (m != 255) ? (float)m : 0.0f;
    const float e_ = __expf(-fabsf(x));
    const float sp = __builtin_amdgcn_rcpf(1.0f + e_);
    const float sn = e_ * sp;
    const bool xp = (x >= 0.0f);
    const bool tp = (t > 0.5f);
    const float prob = xp ? sp : sn;          // sigmoid(x)
    const float pt   = (xp == tp) ? sp : sn;  // prob*t + (1-prob)*(1-t)
    const float om   = (xp == tp) ? sn : sp;  // 1 - pt
    const float bce  = -__logf(pt);
    const float fw   = is_rm ? om * om : 1.0f;
    lsum  += vf * fw * bce;
    inter += prob * t;                        // t==0 when invalid
    ps    += vf * prob;
    ts    += t;
    cnt   += vf;
}

// ---------------- streaming rm+da: 2-deep software pipeline ----------------
// y in [0,24): rm channel y ; y in [24,32): da batch y-24
__global__ __launch_bounds__(TPB, 8) void stream_kernel(
        const float* __restrict__ da_logits,
        const int*   __restrict__ da_mask,
        const float* __restrict__ rm_logits,
        const int*   __restrict__ rm_mask,
        double* __restrict__ acc) {
    __shared__ double smem[4];
    const int y = blockIdx.y;
    const bool is_rm = (y < 24);
    const float* lbase = is_rm ? rm_logits + (size_t)y * SEG
                               : da_logits + (size_t)(y - 24) * SEG;
    const int*   mbase = is_rm ? rm_mask + (size_t)y * SEG
                               : da_mask + (size_t)(y - 24) * SEG;

    const size_t base = (size_t)(blockIdx.x * TPB + threadIdx.x) * 8;
    const float4* lp = (const float4*)(lbase + base);
    const int4*   mp = (const int4*)(mbase + base);

    float lsum = 0.f, inter = 0.f, ps = 0.f, ts = 0.f, cnt = 0.f;

    // prologue: first chunk in flight
    float4 ca0 = lp[0], ca1 = lp[1];
    int4   cb0 = mp[0], cb1 = mp[1];

    #pragma unroll
    for (int it = 0; it < ITERS; ++it) {
        float4 na0, na1; int4 nb0, nb1;
        if (it < ITERS - 1) {
            const int o = (it + 1) * CHUNK_F4;
            na0 = lp[o]; na1 = lp[o + 1];      // issue next-iter loads early;
            nb0 = mp[o]; nb1 = mp[o + 1];      // independent of current compute
        }
        elem_one(ca0.x, cb0.x, is_rm, lsum, inter, ps, ts, cnt);
        elem_one(ca0.y, cb0.y, is_rm, lsum, inter, ps, ts, cnt);
        elem_one(ca0.z, cb0.z, is_rm, lsum, inter, ps, ts, cnt);
        elem_one(ca0.w, cb0.w, is_rm, lsum, inter, ps, ts, cnt);
        elem_one(ca1.x, cb1.x, is_rm, lsum, inter, ps, ts, cnt);
        elem_one(ca1.y, cb1.y, is_rm, lsum, inter, ps, ts, cnt);
        elem_one(ca1.z, cb1.z, is_rm, lsum, inter, ps, ts, cnt);
        elem_one(ca1.w, cb1.w, is_rm, lsum, inter, ps, ts, cnt);
        ca0 = na0; ca1 = na1; cb0 = nb0; cb1 = nb1;
    }

    if (is_rm) {
        reduce_atomic((double)lsum,  &acc[48 + y],  smem);
        reduce_atomic((double)inter, &acc[72 + y],  smem);
        reduce_atomic((double)ps,    &acc[96 + y],  smem);
        reduce_atomic((double)ts,    &acc[120 + y], smem);
        reduce_atomic((double)cnt,   &acc[144 + y], smem);
    } else {
        reduce_atomic((double)lsum, &acc[32 + (y - 24)], smem);
        reduce_atomic((double)cnt,  &acc[40 + (y - 24)], smem);
    }
}

// ---------------- det (OD) ----------------
__global__ void det_kernel(const float* __restrict__ det_logits,
                           const float* __restrict__ det_yolo,
                           double* __restrict__ acc) {
    __shared__ float gt[NBOX * 5];
    __shared__ double smem[4];
    const int b = blockIdx.y;
    const int tid = threadIdx.x;
    const float* g = det_yolo + (size_t)b * NBOX * 5;
    for (int i = tid; i < NBOX * 5; i += blockDim.x) gt[i] = g[i];
    __syncthreads();

    const int cell = blockIdx.x * TPB + tid;   // 25 * 256 == 6400 exactly

    int win = -1;   // last valid box mapping to this cell wins
    #pragma unroll 4
    for (int n = 0; n < NBOX; n++) {
        const int cls = (int)gt[n * 5 + 0];
        const bool valid = (cls >= 0) && (cls < NUM_CLASSES) &&
                           (gt[n * 5 + 3] > 0.0f) && (gt[n * 5 + 4] > 0.0f);
        if (valid) {
            const float cx = fminf(fmaxf(gt[n * 5 + 1], 0.0f), 1.0f);
            const float cy = fminf(fmaxf(gt[n * 5 + 2], 0.0f), 1.0f);
            const int gx = min((int)(cx * (float)GRID_W), GRID_W - 1);
            const int gy = min((int)(cy * (float)GRID_H), GRID_H - 1);
            if (gy * GRID_W + gx == cell) win = n;
        }
    }
    const float* dl = det_logits + (size_t)b * 15 * NCELLS;
    const float x_obj = dl[4 * NCELLS + cell];
    const float tobj = (win >= 0) ? 1.0f : 0.0f;
    float obj;
    {
        const float e  = __expf(-fabsf(x_obj));
        const float sp = __builtin_amdgcn_rcpf(1.0f + e);
        const float sn = e * sp;
        obj = -__logf(((x_obj >= 0.0f) == (tobj > 0.5f)) ? sp : sn);
    }
    float boxl = 0.0f, clsl = 0.0f, posn = 0.0f;
    if (win >= 0) {
        posn = 1.0f;
        #pragma unroll
        for (int k = 0; k < 4; k++) {
            const float xb = dl[k * NCELLS + cell];
            const float e = __expf(-fabsf(xb));
            const float sp = __builtin_amdgcn_rcpf(1.0f + e);
            const float pb = (xb >= 0.0f) ? sp : e * sp;
            const float tc = fminf(fmaxf(gt[win * 5 + 1 + k], 0.0f), 1.0f);
            const float d = fabsf(pb - tc);
            boxl += (d < 1.0f) ? 0.5f * d * d : d - 0.5f;
        }
        float lx[NUM_CLASSES];
        float mx = -INFINITY;
        #pragma unroll
        for (int c = 0; c < NUM_CLASSES; c++) {
            lx[c] = dl[(5 + c) * NCELLS + cell];
            mx = fmaxf(mx, lx[c]);
        }
        float se = 0.0f;
        #pragma unroll
        for (int c = 0; c < NUM_CLASSES; c++) se += __expf(lx[c] - mx);
        const int tcl = (int)gt[win * 5 + 0];
        clsl = -(lx[tcl] - mx - __logf(se));
    }
    reduce_atomic((double)obj,  &acc[0 + b],  smem);
    reduce_atomic((double)boxl, &acc[8 + b],  smem);
    reduce_atomic((double)clsl, &acc[16 + b], smem);
    reduce_atomic((double)posn, &acc[24 + b], smem);
}

// ---------------- finalize ----------------
__global__ void final_kernel(const double* __restrict__ acc,
                             const int* __restrict__ has_det,
                             const int* __restrict__ has_da,
                             const int* __restrict__ has_rm,
                             float* __restrict__ out, int B) {
    if (threadIdx.x != 0 || blockIdx.x != 0) return;
    double od_num = 0.0, wsum = 0.0;
    for (int b = 0; b < B; b++) {
        const double np_ = fmax(acc[24 + b], 1.0);
        const double obj_b = acc[0 + b] / (double)NCELLS;
        const double box_b = acc[8 + b] / (np_ * 4.0);
        const double cls_b = acc[16 + b] / np_;
        const double w = (double)has_det[b];
        od_num += (obj_b + box_b + cls_b) * w;
        wsum += w;
    }
    const double od = od_num / fmax(wsum, 1.0);

    double da_num = 0.0, daw = 0.0;
    for (int b = 0; b < B; b++) {
        const double c = acc[40 + b];
        const double da_b = acc[32 + b] / fmax(c, 1.0);
        const double w = (double)has_da[b] * (c > 0.0 ? 1.0 : 0.0);
        da_num += da_b * w;
        daw += w;
    }
    const double da = da_num / fmax(daw, 1.0);

    double rm_num = 0.0, rmw = 0.0;
    for (int ch = 0; ch < 3 * B; ch++) {
        const double c = acc[144 + ch];
        const double focal = acc[48 + ch] / fmax(c, 1.0);
        const double dice = 1.0 - (2.0 * acc[72 + ch] + 1e-6) /
                                  (acc[96 + ch] + acc[120 + ch] + 1e-6);
        const double w = (double)has_rm[ch] * (c > 0.0 ? 1.0 : 0.0);
        rm_num += (focal + dice) * w;
        rmw += w;
    }
    const double rm = rm_num / fmax(rmw, 1.0);

    const double total = od + da + 2.0 * rm;
    out[0] = (float)total;
    out[1] = (float)od;
    out[2] = (float)da;
    out[3] = (float)rm;
}

extern "C" void kernel_launch(void* const* d_in, const int* in_sizes, int n_in,
                              void* d_out, int out_size, void* d_ws, size_t ws_size,
                              hipStream_t stream) {
    const float* det_logits = (const float*)d_in[0];
    const float* det_yolo   = (const float*)d_in[1];
    const float* da_logits  = (const float*)d_in[2];
    const int*   da_mask    = (const int*)d_in[3];
    const float* rm_logits  = (const float*)d_in[4];
    const int*   rm_mask    = (const int*)d_in[5];
    const int*   has_det    = (const int*)d_in[6];
    const int*   has_da     = (const int*)d_in[7];
    const int*   has_rm     = (const int*)d_in[8];
    float* out = (float*)d_out;
    double* acc = (double*)d_ws;

    const int B = in_sizes[6];   // 8

    hipMemsetAsync(acc, 0, WS_DOUBLES * sizeof(double), stream);

    det_kernel<<<dim3(NCELLS / TPB, B), TPB, 0, stream>>>(det_logits, det_yolo, acc);
    stream_kernel<<<dim3(XBLK, 32), TPB, 0, stream>>>(
        da_logits, da_mask, rm_logits, rm_mask, acc);
    final_kernel<<<1, 64, 0, stream>>>(acc, has_det, has_da, has_rm, out, B);
}

// Round 7
// 97.121 us; speedup vs baseline: 4.1988x; 4.1988x over previous
//
#include <hip/hip_runtime.h>
#include <math.h>

#define NUM_CLASSES 10
#define GRID_H 80
#define GRID_W 80
#define NCELLS (GRID_H * GRID_W)
#define NBOX 64
#define SEG (1024 * 1024)   // Hs*Ws per (batch[,channel])
#define XBLK 128
#define TPB 256
#define ITERS 4             // 128 blk * 256 thr * 8 elem * 4 iter == SEG
#define CH_F4 (XBLK * TPB * 2)   // per-iter stride in float4 units (8 elem/thread)

// ws layout (doubles):
//  0..7    obj_sum[b]
//  8..15   box_sum[b]
// 16..23   cls_sum[b]
// 24..31   npos[b]
// 32..39   da_sum[b]
// 40..47   da_cnt[b]
// 48..71   rm_focal[b*3+c]
// 72..95   rm_inter[ch]
// 96..119  rm_probsum[ch]
// 120..143 rm_rtsum[ch]
// 144..167 rm_cnt[ch]
#define WS_DOUBLES 168

__device__ __forceinline__ void reduce_atomic(double v, double* gdst, double* smem) {
    #pragma unroll
    for (int off = 32; off > 0; off >>= 1) v += __shfl_down(v, off, 64);
    int lane = threadIdx.x & 63, wid = threadIdx.x >> 6;
    __syncthreads();               // protect smem reuse across successive calls
    if (lane == 0) smem[wid] = v;
    __syncthreads();
    if (threadIdx.x == 0) {
        double s = 0.0;
        int nw = blockDim.x >> 6;
        for (int i = 0; i < nw; i++) s += smem[i];
        atomicAdd(gdst, s);
    }
}

// one element of rm/da math; t in {0,1}; is_rm selects focal weighting
__device__ __forceinline__ void elem_one(float x, int m, bool is_rm,
        float& lsum, float& inter, float& ps, float& ts, float& cnt) {
    const float vf = (m != 255) ? 1.0f : 0.0f;
    const float t  = (m != 255) ? (float)m : 0.0f;
    const float e_ = __expf(-fabsf(x));
    const float sp = __builtin_amdgcn_rcpf(1.0f + e_);
    const float sn = e_ * sp;
    const bool xp = (x >= 0.0f);
    const bool tp = (t > 0.5f);
    const float prob = xp ? sp : sn;          // sigmoid(x)
    const float pt   = (xp == tp) ? sp : sn;  // prob*t + (1-prob)*(1-t)
    const float om   = (xp == tp) ? sn : sp;  // 1 - pt
    const float bce  = -__logf(pt);
    const float fw   = is_rm ? om * om : 1.0f;
    lsum  += vf * fw * bce;
    inter += prob * t;                        // t==0 when invalid
    ps    += vf * prob;
    ts    += t;
    cnt   += vf;
}

#define COMPUTE8(A0, A1, B0, B1)                                          \
    do {                                                                  \
        elem_one(A0.x, B0.x, is_rm, lsum, inter, ps, ts, cnt);            \
        elem_one(A0.y, B0.y, is_rm, lsum, inter, ps, ts, cnt);            \
        elem_one(A0.z, B0.z, is_rm, lsum, inter, ps, ts, cnt);            \
        elem_one(A0.w, B0.w, is_rm, lsum, inter, ps, ts, cnt);            \
        elem_one(A1.x, B1.x, is_rm, lsum, inter, ps, ts, cnt);            \
        elem_one(A1.y, B1.y, is_rm, lsum, inter, ps, ts, cnt);            \
        elem_one(A1.z, B1.z, is_rm, lsum, inter, ps, ts, cnt);            \
        elem_one(A1.w, B1.w, is_rm, lsum, inter, ps, ts, cnt);            \
    } while (0)

// ---------------- streaming rm+da: depth-2 pipeline, unroll pinned ----------------
// y in [0,24): rm channel y ; y in [24,32): da batch y-24
__global__ __launch_bounds__(TPB, 8) void stream_kernel(
        const float* __restrict__ da_logits,
        const int*   __restrict__ da_mask,
        const float* __restrict__ rm_logits,
        const int*   __restrict__ rm_mask,
        double* __restrict__ acc) {
    __shared__ double smem[4];
    const int y = blockIdx.y;
    const bool is_rm = (y < 24);
    const float* lbase = is_rm ? rm_logits + (size_t)y * SEG
                               : da_logits + (size_t)(y - 24) * SEG;
    const int*   mbase = is_rm ? rm_mask + (size_t)y * SEG
                               : da_mask + (size_t)(y - 24) * SEG;

    const size_t base = (size_t)(blockIdx.x * TPB + threadIdx.x) * 8;
    const float4* lp = (const float4*)(lbase + base);
    const int4*   mp = (const int4*)(mbase + base);

    float lsum = 0.f, inter = 0.f, ps = 0.f, ts = 0.f, cnt = 0.f;

    // prologue: first chunk in flight
    float4 ca0 = lp[0], ca1 = lp[1];
    int4   cb0 = mp[0], cb1 = mp[1];

    #pragma unroll 1
    for (int it = 0; it < ITERS - 1; ++it) {
        const int o = (it + 1) * CH_F4;
        // issue next-iter loads early; independent of current compute
        float4 na0 = lp[o], na1 = lp[o + 1];
        int4   nb0 = mp[o], nb1 = mp[o + 1];
        COMPUTE8(ca0, ca1, cb0, cb1);
        ca0 = na0; ca1 = na1; cb0 = nb0; cb1 = nb1;
    }
    // epilogue: last chunk
    COMPUTE8(ca0, ca1, cb0, cb1);

    if (is_rm) {
        reduce_atomic((double)lsum,  &acc[48 + y],  smem);
        reduce_atomic((double)inter, &acc[72 + y],  smem);
        reduce_atomic((double)ps,    &acc[96 + y],  smem);
        reduce_atomic((double)ts,    &acc[120 + y], smem);
        reduce_atomic((double)cnt,   &acc[144 + y], smem);
    } else {
        reduce_atomic((double)lsum, &acc[32 + (y - 24)], smem);
        reduce_atomic((double)cnt,  &acc[40 + (y - 24)], smem);
    }
}

// ---------------- det (OD) ----------------
__global__ void det_kernel(const float* __restrict__ det_logits,
                           const float* __restrict__ det_yolo,
                           double* __restrict__ acc) {
    __shared__ float gt[NBOX * 5];
    __shared__ double smem[4];
    const int b = blockIdx.y;
    const int tid = threadIdx.x;
    const float* g = det_yolo + (size_t)b * NBOX * 5;
    for (int i = tid; i < NBOX * 5; i += blockDim.x) gt[i] = g[i];
    __syncthreads();

    const int cell = blockIdx.x * TPB + tid;   // 25 * 256 == 6400 exactly

    int win = -1;   // last valid box mapping to this cell wins
    #pragma unroll 4
    for (int n = 0; n < NBOX; n++) {
        const int cls = (int)gt[n * 5 + 0];
        const bool valid = (cls >= 0) && (cls < NUM_CLASSES) &&
                           (gt[n * 5 + 3] > 0.0f) && (gt[n * 5 + 4] > 0.0f);
        if (valid) {
            const float cx = fminf(fmaxf(gt[n * 5 + 1], 0.0f), 1.0f);
            const float cy = fminf(fmaxf(gt[n * 5 + 2], 0.0f), 1.0f);
            const int gx = min((int)(cx * (float)GRID_W), GRID_W - 1);
            const int gy = min((int)(cy * (float)GRID_H), GRID_H - 1);
            if (gy * GRID_W + gx == cell) win = n;
        }
    }
    const float* dl = det_logits + (size_t)b * 15 * NCELLS;
    const float x_obj = dl[4 * NCELLS + cell];
    const float tobj = (win >= 0) ? 1.0f : 0.0f;
    float obj;
    {
        const float e  = __expf(-fabsf(x_obj));
        const float sp = __builtin_amdgcn_rcpf(1.0f + e);
        const float sn = e * sp;
        obj = -__logf(((x_obj >= 0.0f) == (tobj > 0.5f)) ? sp : sn);
    }
    float boxl = 0.0f, clsl = 0.0f, posn = 0.0f;
    if (win >= 0) {
        posn = 1.0f;
        #pragma unroll
        for (int k = 0; k < 4; k++) {
            const float xb = dl[k * NCELLS + cell];
            const float e = __expf(-fabsf(xb));
            const float sp = __builtin_amdgcn_rcpf(1.0f + e);
            const float pb = (xb >= 0.0f) ? sp : e * sp;
            const float tc = fminf(fmaxf(gt[win * 5 + 1 + k], 0.0f), 1.0f);
            const float d = fabsf(pb - tc);
            boxl += (d < 1.0f) ? 0.5f * d * d : d - 0.5f;
        }
        float lx[NUM_CLASSES];
        float mx = -INFINITY;
        #pragma unroll
        for (int c = 0; c < NUM_CLASSES; c++) {
            lx[c] = dl[(5 + c) * NCELLS + cell];
            mx = fmaxf(mx, lx[c]);
        }
        float se = 0.0f;
        #pragma unroll
        for (int c = 0; c < NUM_CLASSES; c++) se += __expf(lx[c] - mx);
        const int tcl = (int)gt[win * 5 + 0];
        clsl = -(lx[tcl] - mx - __logf(se));
    }
    reduce_atomic((double)obj,  &acc[0 + b],  smem);
    reduce_atomic((double)boxl, &acc[8 + b],  smem);
    reduce_atomic((double)clsl, &acc[16 + b], smem);
    reduce_atomic((double)posn, &acc[24 + b], smem);
}

// ---------------- finalize ----------------
__global__ void final_kernel(const double* __restrict__ acc,
                             const int* __restrict__ has_det,
                             const int* __restrict__ has_da,
                             const int* __restrict__ has_rm,
                             float* __restrict__ out, int B) {
    if (threadIdx.x != 0 || blockIdx.x != 0) return;
    double od_num = 0.0, wsum = 0.0;
    for (int b = 0; b < B; b++) {
        const double np_ = fmax(acc[24 + b], 1.0);
        const double obj_b = acc[0 + b] / (double)NCELLS;
        const double box_b = acc[8 + b] / (np_ * 4.0);
        const double cls_b = acc[16 + b] / np_;
        const double w = (double)has_det[b];
        od_num += (obj_b + box_b + cls_b) * w;
        wsum += w;
    }
    const double od = od_num / fmax(wsum, 1.0);

    double da_num = 0.0, daw = 0.0;
    for (int b = 0; b < B; b++) {
        const double c = acc[40 + b];
        const double da_b = acc[32 + b] / fmax(c, 1.0);
        const double w = (double)has_da[b] * (c > 0.0 ? 1.0 : 0.0);
        da_num += da_b * w;
        daw += w;
    }
    const double da = da_num / fmax(daw, 1.0);

    double rm_num = 0.0, rmw = 0.0;
    for (int ch = 0; ch < 3 * B; ch++) {
        const double c = acc[144 + ch];
        const double focal = acc[48 + ch] / fmax(c, 1.0);
        const double dice = 1.0 - (2.0 * acc[72 + ch] + 1e-6) /
                                  (acc[96 + ch] + acc[120 + ch] + 1e-6);
        const double w = (double)has_rm[ch] * (c > 0.0 ? 1.0 : 0.0);
        rm_num += (focal + dice) * w;
        rmw += w;
    }
    const double rm = rm_num / fmax(rmw, 1.0);

    const double total = od + da + 2.0 * rm;
    out[0] = (float)total;
    out[1] = (float)od;
    out[2] = (float)da;
    out[3] = (float)rm;
}

extern "C" void kernel_launch(void* const* d_in, const int* in_sizes, int n_in,
                              void* d_out, int out_size, void* d_ws, size_t ws_size,
                              hipStream_t stream) {
    const float* det_logits = (const float*)d_in[0];
    const float* det_yolo   = (const float*)d_in[1];
    const float* da_logits  = (const float*)d_in[2];
    const int*   da_mask    = (const int*)d_in[3];
    const float* rm_logits  = (const float*)d_in[4];
    const int*   rm_mask    = (const int*)d_in[5];
    const int*   has_det    = (const int*)d_in[6];
    const int*   has_da     = (const int*)d_in[7];
    const int*   has_rm     = (const int*)d_in[8];
    float* out = (float*)d_out;
    double* acc = (double*)d_ws;

    const int B = in_sizes[6];   // 8

    hipMemsetAsync(acc, 0, WS_DOUBLES * sizeof(double), stream);

    det_kernel<<<dim3(NCELLS / TPB, B), TPB, 0, stream>>>(det_logits, det_yolo, acc);
    stream_kernel<<<dim3(XBLK, 32), TPB, 0, stream>>>(
        da_logits, da_mask, rm_logits, rm_mask, acc);
    final_kernel<<<1, 64, 0, stream>>>(acc, has_det, has_da, has_rm, out, B);
}